// Round 6
// baseline (26587.585 us; speedup 1.0000x reference)
//
#include <hip/hip_runtime.h>
#include <hip/hip_bf16.h>
#include <stdint.h>

// SequenceDecoder: B=64, LATENT=512, H=1024, V=8192, T=128
#define BB 64
#define LAT 512
#define HH 1024
#define VV 8192
#define TT 128

typedef short bf16x8 __attribute__((ext_vector_type(8)));
typedef float f32x4 __attribute__((ext_vector_type(4)));
typedef unsigned long long u64;

__device__ __forceinline__ unsigned short f2bf(float f) {
    union { float f; unsigned int u; } a; a.f = f;
    unsigned int u = a.u;
    return (unsigned short)((u + 0x7FFFu + ((u >> 16) & 1u)) >> 16);   // RNE
}
__device__ __forceinline__ float bf2f(unsigned short b) {
    union { unsigned int u; float f; } a; a.u = ((unsigned int)b) << 16;
    return a.f;
}
__device__ __forceinline__ void split8(const float* __restrict__ p, bf16x8& hi, bf16x8& lo) {
#pragma unroll
    for (int i = 0; i < 8; ++i) {
        float v = p[i];
        unsigned short h = f2bf(v);
        hi[i] = (short)h;
        lo[i] = (short)f2bf(v - bf2f(h));
    }
}

// device-wide barrier, system-scope hardened (cross-XCD L2 writeback+inv).
// All 256 blocks co-resident: 138 KB LDS forces 1 block/CU, grid == 256 CUs.
__device__ __forceinline__ void gridbar(unsigned int* ctr, unsigned int& epoch) {
    __threadfence_system();           // release: write-back dirty L2 lines
    __syncthreads();
    ++epoch;
    if (threadIdx.x == 0) {
        __hip_atomic_fetch_add(ctr, 1u, __ATOMIC_ACQ_REL, __HIP_MEMORY_SCOPE_SYSTEM);
        const unsigned int tgt = epoch * 256u;
        while (__hip_atomic_load(ctr, __ATOMIC_ACQUIRE, __HIP_MEMORY_SCOPE_SYSTEM) < tgt)
            __builtin_amdgcn_s_sleep(2);
    }
    __syncthreads();
    __threadfence_system();           // acquire: invalidate local caches
}

// ---------------------------------------------------------------------------
// split fp32 -> (hi, lo) bf16.  n4 = n/4 float4 groups.
// ---------------------------------------------------------------------------
__global__ __launch_bounds__(256) void split_kernel(
    const float* __restrict__ src, unsigned short* __restrict__ hi,
    unsigned short* __restrict__ lo, int n4)
{
    int i = blockIdx.x * 256 + threadIdx.x;
    if (i >= n4) return;
    float4 v = ((const float4*)src)[i];
    ushort4 h, l;
    h.x = f2bf(v.x); l.x = f2bf(v.x - bf2f(h.x));
    h.y = f2bf(v.y); l.y = f2bf(v.y - bf2f(h.y));
    h.z = f2bf(v.z); l.z = f2bf(v.z - bf2f(h.z));
    h.w = f2bf(v.w); l.w = f2bf(v.w - bf2f(h.w));
    ((ushort4*)hi)[i] = h;
    ((ushort4*)lo)[i] = l;
}

// ---------------------------------------------------------------------------
// init: h0 = z @ W_lat.T + b_lat (split store, set 0); parts bootstrap; ctr=0
// ---------------------------------------------------------------------------
__global__ __launch_bounds__(512) void init_kernel(
    const float* __restrict__ z, const float* __restrict__ W_lat,
    const float* __restrict__ b_lat, unsigned short* __restrict__ h0_hi,
    unsigned short* __restrict__ h0_lo, u64* __restrict__ parts,
    unsigned int* __restrict__ ctr)
{
    __shared__ float z_lds[BB][64];
    const int tid = threadIdx.x;
    const int lane = tid & 63;
    const int w = tid >> 6;
    const int rbase = blockIdx.x * 32 + w * 4;

    float acc[4] = {0.f, 0.f, 0.f, 0.f};
    for (int k0 = 0; k0 < LAT; k0 += 64) {
        __syncthreads();
        for (int i = tid; i < BB * 16; i += 512) {
            int row = i / 16, g = i % 16, gs = g ^ (row & 7);
            *(float4*)&z_lds[row][gs * 4] =
                *(const float4*)(z + (size_t)row * LAT + k0 + g * 4);
        }
        __syncthreads();
        const float* wp = W_lat + (size_t)__builtin_amdgcn_readfirstlane(rbase) * LAT + k0;
#pragma unroll
        for (int g = 0; g < 16; ++g) {
            int gs = g ^ (lane & 7);
            float4 zv = *(const float4*)&z_lds[lane][gs * 4];
#pragma unroll
            for (int r = 0; r < 4; ++r) {
                float4 wv = *(const float4*)(wp + (size_t)r * LAT + g * 4);
                acc[r] += zv.x * wv.x + zv.y * wv.y + zv.z * wv.z + zv.w * wv.w;
            }
        }
    }
#pragma unroll
    for (int r = 0; r < 4; ++r) {
        int row = rbase + r;
        float hv = acc[r] + b_lat[row];
        unsigned short hb = f2bf(hv);
        h0_hi[(size_t)lane * HH + row] = hb;
        h0_lo[(size_t)lane * HH + row] = f2bf(hv - bf2f(hb));
    }
    // parts: 2 sets x 16 shards x 64.  set1 shard0 = ~0 -> tok(0) = 0.
    int gid = blockIdx.x * 512 + tid;
    if (gid < 2048)
        parts[gid] = (gid >= 1024 && gid < 1088) ? 0xFFFFFFFFull : 0ull;
    if (blockIdx.x == 0 && tid < 16) ctr[tid] = 0u;
}

// ---------------------------------------------------------------------------
// persistent weight-stationary decoder.  grid 256 x 512 (8 waves).
// Block owns: gates rows (4 gates x 4 j, j = blk*4..+3) and logits rows
// blk*32..+31.  Wave w owns K-slice [w*128, w*128+128).
// Weights: W_ih/W_hh hi+lo and W_out hi in VGPRs, W_out lo in LDS (swizzled).
// Per step: phase G (gates+cell) -> gridbar -> phase L (logits+argmax) -> gridbar.
// ---------------------------------------------------------------------------
__global__ __launch_bounds__(512, 2) void decoder_persistent(
    const unsigned short* __restrict__ E_hi, const unsigned short* __restrict__ E_lo,
    const float* __restrict__ W_ih, const float* __restrict__ W_hh,
    const float* __restrict__ W_out,
    const float* __restrict__ b_ih, const float* __restrict__ b_hh,
    const float* __restrict__ b_out,
    unsigned short* __restrict__ h_hi, unsigned short* __restrict__ h_lo,
    u64* __restrict__ parts, unsigned int* __restrict__ bar_ctr,
    float* __restrict__ out)
{
    __shared__ __attribute__((aligned(16))) char wlo_lds[65536]; // Wout_lo [32][1024]
    __shared__ float red[8][32][66];     // cross-wave reduce (G: m<16, L: m<32)
    __shared__ u64 keyred[8][64];
    __shared__ int s_tok[BB];
    __shared__ float c_lds[4][BB];

    const int tid = threadIdx.x;
    const int lane = tid & 63;
    const int w = tid >> 6;
    const int lrow = lane & 15;
    const int kgrp = lane >> 4;
    const int blk = blockIdx.x;
    const int wk0 = w * 128;

    // ---- startup: weights -> regs / LDS --------------------------------
    bf16x8 wih_hi[4], wih_lo[4], whh_hi[4], whh_lo[4], wo_hi[2][4];
    {
        const int grow = (lrow >> 2) * HH + blk * 4 + (lrow & 3);
#pragma unroll
        for (int ch = 0; ch < 4; ++ch) {
            const int k = wk0 + ch * 32 + kgrp * 8;
            split8(W_ih + (size_t)grow * HH + k, wih_hi[ch], wih_lo[ch]);
            split8(W_hh + (size_t)grow * HH + k, whh_hi[ch], whh_lo[ch]);
        }
#pragma unroll
        for (int rt = 0; rt < 2; ++rt) {
            const int row = rt * 16 + lrow;
            const int orow = blk * 32 + row;
#pragma unroll
            for (int ch = 0; ch < 4; ++ch) {
                const int k = wk0 + ch * 32 + kgrp * 8;
                bf16x8 lo;
                split8(W_out + (size_t)orow * HH + k, wo_hi[rt][ch], lo);
                *(bf16x8*)(wlo_lds + ((row * 2048 + k * 2) ^ ((row & 7) << 4))) = lo;
            }
        }
    }
    float bias_g[4] = {0.f, 0.f, 0.f, 0.f};
    if (tid < 256) {
        const int jj = tid >> 6, b = tid & 63;
#pragma unroll
        for (int g = 0; g < 4; ++g)
            bias_g[g] = b_ih[g * HH + blk * 4 + jj] + b_hh[g * HH + blk * 4 + jj];
        c_lds[jj][b] = 0.f;
    }
    const float4 bo4 = *(const float4*)(b_out + blk * 32 + (tid >> 6) * 4);
    __syncthreads();

    unsigned int epoch = 0;

    for (int t = 0; t < TT; ++t) {
        const unsigned short* hp_h = h_hi + (t & 1) * (BB * HH);
        const unsigned short* hp_l = h_lo + (t & 1) * (BB * HH);
        unsigned short* hn_h = h_hi + ((t + 1) & 1) * (BB * HH);
        unsigned short* hn_l = h_lo + ((t + 1) & 1) * (BB * HH);
        u64* rd = parts + ((t + 1) & 1) * 1024;
        u64* zw = parts + (t & 1) * 1024;

        // token resolve (16 shards, atomic loads) + zero this step's shard set
        if (tid < BB) {
            u64 mk = 0;
#pragma unroll
            for (int s = 0; s < 16; ++s) {
                u64 k = __hip_atomic_load(&rd[s * 64 + tid], __ATOMIC_RELAXED,
                                          __HIP_MEMORY_SCOPE_AGENT);
                mk = mk > k ? mk : k;
            }
            s_tok[tid] = (int)(~(unsigned int)(mk & 0xFFFFFFFFull)) & (VV - 1);
        }
        if (blk < 16 && tid < BB)
            __hip_atomic_store(&zw[blk * 64 + tid], 0ull, __ATOMIC_RELAXED,
                               __HIP_MEMORY_SCOPE_AGENT);
        __syncthreads();

        // ---- phase G: gates GEMM (full split: 3-term x, 3-term h) ----
        f32x4 gacc[4];
#pragma unroll
        for (int bt = 0; bt < 4; ++bt) gacc[bt] = (f32x4){0.f, 0.f, 0.f, 0.f};
#pragma unroll
        for (int bt = 0; bt < 4; ++bt) {
            const int b = bt * 16 + lrow;
            const unsigned short* xrh = E_hi + (size_t)s_tok[b] * HH + wk0;
            const unsigned short* xrl = E_lo + (size_t)s_tok[b] * HH + wk0;
            const unsigned short* hrh = hp_h + (size_t)b * HH + wk0;
            const unsigned short* hrl = hp_l + (size_t)b * HH + wk0;
#pragma unroll
            for (int ch = 0; ch < 4; ++ch) {
                const int ko = ch * 32 + kgrp * 8;
                bf16x8 xh = *(const bf16x8*)(xrh + ko);
                bf16x8 xl = *(const bf16x8*)(xrl + ko);
                bf16x8 hv = *(const bf16x8*)(hrh + ko);
                bf16x8 lv = *(const bf16x8*)(hrl + ko);
                gacc[bt] = __builtin_amdgcn_mfma_f32_16x16x32_bf16(wih_hi[ch], xh, gacc[bt], 0, 0, 0);
                gacc[bt] = __builtin_amdgcn_mfma_f32_16x16x32_bf16(wih_hi[ch], xl, gacc[bt], 0, 0, 0);
                gacc[bt] = __builtin_amdgcn_mfma_f32_16x16x32_bf16(wih_lo[ch], xh, gacc[bt], 0, 0, 0);
                gacc[bt] = __builtin_amdgcn_mfma_f32_16x16x32_bf16(whh_hi[ch], hv, gacc[bt], 0, 0, 0);
                gacc[bt] = __builtin_amdgcn_mfma_f32_16x16x32_bf16(whh_hi[ch], lv, gacc[bt], 0, 0, 0);
                gacc[bt] = __builtin_amdgcn_mfma_f32_16x16x32_bf16(whh_lo[ch], hv, gacc[bt], 0, 0, 0);
            }
        }
#pragma unroll
        for (int bt = 0; bt < 4; ++bt)
#pragma unroll
            for (int r = 0; r < 4; ++r)
                red[w][kgrp * 4 + r][bt * 16 + lrow] = gacc[bt][r];
        __syncthreads();

        // ---- cell update (threads 0..255: jj = tid>>6, b = tid&63) ----
        if (tid < 256) {
            const int jj = tid >> 6, b = tid & 63;
            float pre[4];
#pragma unroll
            for (int g = 0; g < 4; ++g) {
                const int m = g * 4 + jj;
                float s = bias_g[g];
#pragma unroll
                for (int ww = 0; ww < 8; ++ww) s += red[ww][m][b];
                pre[g] = s;
            }
            float iv = 1.f / (1.f + expf(-pre[0]));
            float fv = 1.f / (1.f + expf(-pre[1]));
            float gv = tanhf(pre[2]);
            float ov = 1.f / (1.f + expf(-pre[3]));
            float cn = fv * c_lds[jj][b] + iv * gv;
            c_lds[jj][b] = cn;
            float hvf = ov * tanhf(cn);
            unsigned short hb = f2bf(hvf);
            hn_h[(size_t)b * HH + blk * 4 + jj] = hb;
            hn_l[(size_t)b * HH + blk * 4 + jj] = f2bf(hvf - bf2f(hb));
        }
        gridbar(bar_ctr, epoch);

        // ---- phase L: logits GEMM ----
        bf16x8 wlo_[2][4];
#pragma unroll
        for (int rt = 0; rt < 2; ++rt)
#pragma unroll
            for (int ch = 0; ch < 4; ++ch) {
                const int row = rt * 16 + lrow;
                const int kb = (wk0 + ch * 32 + kgrp * 8) * 2;
                wlo_[rt][ch] = *(const bf16x8*)(wlo_lds + ((row * 2048 + kb) ^ ((row & 7) << 4)));
            }
        f32x4 lacc[2][4];
#pragma unroll
        for (int rt = 0; rt < 2; ++rt)
#pragma unroll
            for (int bt = 0; bt < 4; ++bt) lacc[rt][bt] = (f32x4){0.f, 0.f, 0.f, 0.f};
#pragma unroll
        for (int bt = 0; bt < 4; ++bt) {
            const int b = bt * 16 + lrow;
            const unsigned short* hrh = hn_h + (size_t)b * HH + wk0;
            const unsigned short* hrl = hn_l + (size_t)b * HH + wk0;
#pragma unroll
            for (int ch = 0; ch < 4; ++ch) {
                const int ko = ch * 32 + kgrp * 8;
                bf16x8 hv = *(const bf16x8*)(hrh + ko);
                bf16x8 lv = *(const bf16x8*)(hrl + ko);
#pragma unroll
                for (int rt = 0; rt < 2; ++rt) {
                    lacc[rt][bt] = __builtin_amdgcn_mfma_f32_16x16x32_bf16(wo_hi[rt][ch], hv, lacc[rt][bt], 0, 0, 0);
                    lacc[rt][bt] = __builtin_amdgcn_mfma_f32_16x16x32_bf16(wo_hi[rt][ch], lv, lacc[rt][bt], 0, 0, 0);
                    lacc[rt][bt] = __builtin_amdgcn_mfma_f32_16x16x32_bf16(wlo_[rt][ch], hv, lacc[rt][bt], 0, 0, 0);
                }
            }
        }
#pragma unroll
        for (int rt = 0; rt < 2; ++rt)
#pragma unroll
            for (int bt = 0; bt < 4; ++bt)
#pragma unroll
                for (int r = 0; r < 4; ++r)
                    red[w][rt * 16 + kgrp * 4 + r][bt * 16 + lrow] = lacc[rt][bt][r];
        __syncthreads();

        // ---- epilogue: bias + nontemporal store + argmax ----
        {
            const int b = tid & 63, mg = tid >> 6;
            f32x4 val;
#pragma unroll
            for (int r = 0; r < 4; ++r) {
                const int m = mg * 4 + r;
                float s = 0.f;
#pragma unroll
                for (int ww = 0; ww < 8; ++ww) s += red[ww][m][b];
                val[r] = s;
            }
            val[0] += bo4.x; val[1] += bo4.y; val[2] += bo4.z; val[3] += bo4.w;
            __builtin_nontemporal_store(val,
                (f32x4*)(out + (size_t)b * (TT * VV) + (size_t)t * VV + blk * 32 + mg * 4));
            u64 best = 0ull;
#pragma unroll
            for (int r = 0; r < 4; ++r) {
                unsigned int row = (unsigned int)(blk * 32 + mg * 4 + r);
                union { float f; unsigned int u; } a; a.f = val[r];
                unsigned int key32 = (a.u & 0x80000000u) ? ~a.u : (a.u | 0x80000000u);
                u64 key = ((u64)key32 << 32) | (u64)(~row);
                best = best > key ? best : key;
            }
            keyred[mg][b] = best;
        }
        __syncthreads();
        if (tid < BB) {
            u64 m = keyred[0][tid];
#pragma unroll
            for (int g = 1; g < 8; ++g) { u64 v = keyred[g][tid]; m = m > v ? m : v; }
            atomicMax(&zw[(blk & 15) * 64 + tid], m);
        }
        gridbar(bar_ctr, epoch);
    }
}

// ---------------------------------------------------------------------------
extern "C" void kernel_launch(void* const* d_in, const int* in_sizes, int n_in,
                              void* d_out, int out_size, void* d_ws, size_t ws_size,
                              hipStream_t stream)
{
    const float* z     = (const float*)d_in[0];
    const float* E     = (const float*)d_in[1];
    const float* W_ih  = (const float*)d_in[2];
    const float* W_hh  = (const float*)d_in[3];
    const float* b_ih  = (const float*)d_in[4];
    const float* b_hh  = (const float*)d_in[5];
    const float* W_lat = (const float*)d_in[6];
    const float* b_lat = (const float*)d_in[7];
    const float* W_out = (const float*)d_in[8];
    const float* b_out = (const float*)d_in[9];
    float* out = (float*)d_out;

    // ws carve (ushort units)
    unsigned short* us   = (unsigned short*)d_ws;
    unsigned short* E_hi = us;                              // 8,388,608
    unsigned short* E_lo = us + 8388608;                    // 8,388,608
    unsigned short* h_hi = us + 16777216;                   // 2 x 65536
    unsigned short* h_lo = us + 16908288;                   // 2 x 65536
    u64* parts = (u64*)(us + 17039360);                     // 2 x 1024
    unsigned int* ctr = (unsigned int*)(parts + 2048);      // barrier counter

    split_kernel<<<8192, 256, 0, stream>>>(E, E_hi, E_lo, VV * HH / 4);
    init_kernel<<<32, 512, 0, stream>>>(z, W_lat, b_lat, h_hi, h_lo, parts, ctr);
    decoder_persistent<<<256, 512, 0, stream>>>(
        E_hi, E_lo, W_ih, W_hh, W_out, b_ih, b_hh, b_out,
        h_hi, h_lo, parts, ctr, out);
}